// Round 1
// baseline (150.370 us; speedup 1.0000x reference)
//
#include <hip/hip_runtime.h>

typedef __bf16 bf16;
typedef __bf16 bf16x8 __attribute__((ext_vector_type(8)));
typedef float f32x4 __attribute__((ext_vector_type(4)));

#define S_LEN 3072
#define E_DIM 1280
#define H_NUM 16
#define D_DIM 80
#define D_PAD 96
#define F3 3840
#define N_SEG 6

__device__ __forceinline__ f32x4 mfma16(bf16x8 a, bf16x8 b, f32x4 c) {
  return __builtin_amdgcn_mfma_f32_16x16x32_bf16(a, b, c, 0, 0, 0);
}

using gas_void = const __attribute__((address_space(1))) void;
using las_void = __attribute__((address_space(3))) void;

__device__ __forceinline__ void async_cp16(const void* g, void* l) {
  // global -> LDS direct copy, 16B per lane; LDS dest = wave-uniform base + lane*16
  __builtin_amdgcn_global_load_lds((gas_void*)g, (las_void*)l, 16, 0, 0);
}

// ---------------- prep: fp32->bf16 casts + rope cos/sin tables ----------------
__global__ void prep_kernel(const float* __restrict__ x, const float* __restrict__ wq,
                            const float* __restrict__ wp, const float* __restrict__ freqs,
                            bf16* __restrict__ xb, bf16* __restrict__ wqb,
                            bf16* __restrict__ wpb, float* __restrict__ cost,
                            float* __restrict__ sint)
{
  const int NX = S_LEN * E_DIM;
  const int NWQ = F3 * E_DIM;
  const int NWP = E_DIM * E_DIM;
  const int NCS = S_LEN * D_DIM;
  const int total = NX + NWQ + NWP + NCS;
  for (int i = blockIdx.x * blockDim.x + threadIdx.x; i < total;
       i += gridDim.x * blockDim.x) {
    if (i < NX) {
      xb[i] = (bf16)x[i];
    } else if (i < NX + NWQ) {
      int j = i - NX; wqb[j] = (bf16)wq[j];
    } else if (i < NX + NWQ + NWP) {
      int j = i - NX - NWQ; wpb[j] = (bf16)wp[j];
    } else {
      int j = i - NX - NWQ - NWP;
      int s = j / D_DIM, d = j - s * D_DIM;
      float f = freqs[s * (D_DIM / 2) + (d % (D_DIM / 2))];
      float sv, cv;
      __sincosf(f, &sv, &cv);
      cost[j] = cv; sint[j] = sv;
    }
  }
}

// ---------------- GEMM: C[M,N] = A[M,K] * B[N,K]^T + bias, 128x128 tile ----------------
template <int OUT_BF16>
__global__ __launch_bounds__(256) void gemm_bt(const bf16* __restrict__ A,
                                               const bf16* __restrict__ B,
                                               const float* __restrict__ bias,
                                               void* __restrict__ Cout,
                                               int M, int N, int K)
{
  __shared__ bf16 Asm[2][128 * 32];
  __shared__ bf16 Bsm[2][128 * 32];
  const int tid = threadIdx.x;
  const int w = tid >> 6, lane = tid & 63;
  const int lr = lane & 15, lg = lane >> 4;
  const int m0 = blockIdx.y * 128, n0 = blockIdx.x * 128;
  const int wr = w >> 1, wc = w & 1;
  (void)M;

  const f32x4 zero4 = {0.f, 0.f, 0.f, 0.f};
  f32x4 acc[4][4];
#pragma unroll
  for (int m = 0; m < 4; ++m)
#pragma unroll
    for (int n = 0; n < 4; ++n) acc[m][n] = zero4;

  const int srow = lane >> 2;        // 0..15
  const int skk = (lane & 3) * 8;    // 0,8,16,24
  const int nk = K / 32;

  {
    const bf16* Ag = A + (size_t)(m0 + w * 32 + srow) * K + skk;
    const bf16* Bg = B + (size_t)(n0 + w * 32 + srow) * K + skk;
    async_cp16(Ag, &Asm[0][w * 1024]);
    async_cp16(Ag + (size_t)16 * K, &Asm[0][w * 1024 + 512]);
    async_cp16(Bg, &Bsm[0][w * 1024]);
    async_cp16(Bg + (size_t)16 * K, &Bsm[0][w * 1024 + 512]);
  }
  for (int t = 0; t < nk; ++t) {
    __syncthreads();  // drains vmcnt: tile t staged; prev compute reads done
    if (t + 1 < nk) {
      const int b = (t + 1) & 1;
      const bf16* Ag = A + (size_t)(m0 + w * 32 + srow) * K + (t + 1) * 32 + skk;
      const bf16* Bg = B + (size_t)(n0 + w * 32 + srow) * K + (t + 1) * 32 + skk;
      async_cp16(Ag, &Asm[b][w * 1024]);
      async_cp16(Ag + (size_t)16 * K, &Asm[b][w * 1024 + 512]);
      async_cp16(Bg, &Bsm[b][w * 1024]);
      async_cp16(Bg + (size_t)16 * K, &Bsm[b][w * 1024 + 512]);
    }
    const bf16* As = Asm[t & 1];
    const bf16* Bs = Bsm[t & 1];
    bf16x8 af[4], bfr[4];
#pragma unroll
    for (int m = 0; m < 4; ++m)
      af[m] = *(const bf16x8*)&As[(wr * 64 + m * 16 + lr) * 32 + lg * 8];
#pragma unroll
    for (int n = 0; n < 4; ++n)
      bfr[n] = *(const bf16x8*)&Bs[(wc * 64 + n * 16 + lr) * 32 + lg * 8];
#pragma unroll
    for (int m = 0; m < 4; ++m)
#pragma unroll
      for (int n = 0; n < 4; ++n)
        acc[m][n] = mfma16(af[m], bfr[n], acc[m][n]);
  }

#pragma unroll
  for (int m = 0; m < 4; ++m) {
    const int row = m0 + wr * 64 + m * 16 + lg * 4;  // C row=(lane>>4)*4+reg, col=lane&15
#pragma unroll
    for (int n = 0; n < 4; ++n) {
      const int col = n0 + wc * 64 + n * 16 + lr;
      const float bv = bias[col];
#pragma unroll
      for (int i = 0; i < 4; ++i) {
        float v = acc[m][n][i] + bv;
        if (OUT_BF16)
          ((bf16*)Cout)[(size_t)(row + i) * N + col] = (bf16)v;
        else
          ((float*)Cout)[(size_t)(row + i) * N + col] = v;
      }
    }
  }
}

// ---------------- RoPE: qkv(bf16) -> Qb/Kb (h, s, 96) bf16, scale folded into Q ----------------
__global__ void rope_kernel(const bf16* __restrict__ qkv, const float* __restrict__ cost,
                            const float* __restrict__ sint, bf16* __restrict__ Qb,
                            bf16* __restrict__ Kb)
{
  const float scale = 0.11180339887498949f;  // 1/sqrt(80)
  const int total = H_NUM * S_LEN * D_PAD;
  for (int i = blockIdx.x * blockDim.x + threadIdx.x; i < total;
       i += gridDim.x * blockDim.x) {
    int h = i / (S_LEN * D_PAD);
    int r = i - h * (S_LEN * D_PAD);
    int s = r / D_PAD, dp = r - s * D_PAD;
    if (dp >= D_DIM) { Qb[i] = (bf16)0.f; Kb[i] = (bf16)0.f; continue; }
    size_t base = (size_t)s * F3 + h * D_DIM;
    float qv = (float)qkv[base + dp];
    float kv = (float)qkv[base + E_DIM + dp];
    float qr, kr;
    if (dp < D_DIM / 2) {
      qr = -(float)qkv[base + dp + 40];
      kr = -(float)qkv[base + E_DIM + dp + 40];
    } else {
      qr = (float)qkv[base + dp - 40];
      kr = (float)qkv[base + E_DIM + dp - 40];
    }
    float c = cost[s * D_DIM + dp], sn = sint[s * D_DIM + dp];
    Qb[i] = (bf16)((qv * c + qr * sn) * scale);
    Kb[i] = (bf16)(kv * c + kr * sn);
  }
}

// ---------------- flash attention within segments; 4 waves x 16 q-rows ----------------
__global__ __launch_bounds__(256) void attn_kernel(const bf16* __restrict__ Qb,
                                                   const bf16* __restrict__ Kb,
                                                   const bf16* __restrict__ qkv,
                                                   const int* __restrict__ cu,
                                                   bf16* __restrict__ ctx)
{
  __shared__ bf16 Ksm[64 * 104];      // K tile, stride 104 (bank-conflict-free b128)
  __shared__ bf16 Vsm[80 * 72];       // V^T tile [d][n], stride 72
  __shared__ bf16 Psm[4][16 * 72];    // per-wave P round-trip, stride 72

  const int tid = threadIdx.x;
  const int w = tid >> 6, lane = tid & 63;
  const int lr = lane & 15, lg = lane >> 4;
  const int bid = blockIdx.x;
  const int qt = bid & 7, h = (bid >> 3) & 15, seg = bid >> 7;
  const int s0 = cu[seg];
  const int q0 = s0 + qt * 64 + w * 16;

  bf16x8 qf[3];  // A-frag: row = lane&15, k = (lane>>4)*8 + j (+32 per chunk)
#pragma unroll
  for (int c = 0; c < 3; ++c)
    qf[c] = *(const bf16x8*)&Qb[((size_t)h * S_LEN + q0 + lr) * D_PAD + c * 32 + lg * 8];

  const f32x4 zero4 = {0.f, 0.f, 0.f, 0.f};
  float m_i[4] = {-1e30f, -1e30f, -1e30f, -1e30f};
  float l_i[4] = {0.f, 0.f, 0.f, 0.f};
  f32x4 o[5];
#pragma unroll
  for (int db = 0; db < 5; ++db) o[db] = zero4;

  for (int kt = 0; kt < 8; ++kt) {
    const int n0 = s0 + kt * 64;
    // stage K tile: 64 rows x 96 elems in 8-elem chunks (768 chunks / 256 thr)
#pragma unroll
    for (int it = 0; it < 3; ++it) {
      int q = tid + it * 256;
      int row = q / 12, sd = (q % 12) * 8;
      *(bf16x8*)&Ksm[row * 104 + sd] =
          *(const bf16x8*)&Kb[((size_t)h * S_LEN + n0 + row) * D_PAD + sd];
    }
    // stage V^T: read V rows from qkv, scatter-transpose into Vsm
#pragma unroll
    for (int it = 0; it < 3; ++it) {
      int q = tid + it * 256;
      if (q < 640) {
        int row = q / 10, d0 = (q % 10) * 8;
        bf16x8 v = *(const bf16x8*)&qkv[(size_t)(n0 + row) * F3 + 2560 + h * D_DIM + d0];
#pragma unroll
        for (int j = 0; j < 8; ++j) Vsm[(d0 + j) * 72 + row] = v[j];
      }
    }
    __syncthreads();

    // S = Q K^T (scale pre-folded into Q); 4 col-blocks of 16
    f32x4 sa[4];
#pragma unroll
    for (int nb = 0; nb < 4; ++nb) {
      sa[nb] = zero4;
#pragma unroll
      for (int c = 0; c < 3; ++c) {
        bf16x8 kf = *(const bf16x8*)&Ksm[(nb * 16 + lr) * 104 + c * 32 + lg * 8];
        sa[nb] = mfma16(qf[c], kf, sa[nb]);
      }
    }

    // online softmax: row i lives in lanes sharing lg; reduce across lr (16-lane groups)
    float al[4];
#pragma unroll
    for (int i = 0; i < 4; ++i) {
      float tm = fmaxf(fmaxf(sa[0][i], sa[1][i]), fmaxf(sa[2][i], sa[3][i]));
#pragma unroll
      for (int off = 1; off < 16; off <<= 1) tm = fmaxf(tm, __shfl_xor(tm, off));
      float mnew = fmaxf(m_i[i], tm);
      al[i] = __expf(m_i[i] - mnew);
      float p0 = __expf(sa[0][i] - mnew);
      float p1 = __expf(sa[1][i] - mnew);
      float p2 = __expf(sa[2][i] - mnew);
      float p3 = __expf(sa[3][i] - mnew);
      sa[0][i] = p0; sa[1][i] = p1; sa[2][i] = p2; sa[3][i] = p3;
      float rs = p0 + p1 + p2 + p3;
#pragma unroll
      for (int off = 1; off < 16; off <<= 1) rs += __shfl_xor(rs, off);
      l_i[i] = l_i[i] * al[i] + rs;
      m_i[i] = mnew;
    }
#pragma unroll
    for (int db = 0; db < 5; ++db)
#pragma unroll
      for (int i = 0; i < 4; ++i) o[db][i] *= al[i];

    // P -> LDS (C layout row=(lg*4+i), col=nb*16+lr) then re-read as A-frag
#pragma unroll
    for (int nb = 0; nb < 4; ++nb)
#pragma unroll
      for (int i = 0; i < 4; ++i)
        Psm[w][(lg * 4 + i) * 72 + nb * 16 + lr] = (bf16)sa[nb][i];

#pragma unroll
    for (int c2 = 0; c2 < 2; ++c2) {
      bf16x8 pa = *(const bf16x8*)&Psm[w][lr * 72 + c2 * 32 + lg * 8];
#pragma unroll
      for (int db = 0; db < 5; ++db) {
        bf16x8 vf = *(const bf16x8*)&Vsm[(db * 16 + lr) * 72 + c2 * 32 + lg * 8];
        o[db] = mfma16(pa, vf, o[db]);
      }
    }
    __syncthreads();
  }

#pragma unroll
  for (int i = 0; i < 4; ++i) {
    float inv = 1.f / l_i[i];
    int row = q0 + lg * 4 + i;
#pragma unroll
    for (int db = 0; db < 5; ++db)
      ctx[(size_t)row * E_DIM + h * D_DIM + db * 16 + lr] = (bf16)(o[db][i] * inv);
  }
}

extern "C" void kernel_launch(void* const* d_in, const int* in_sizes, int n_in,
                              void* d_out, int out_size, void* d_ws, size_t ws_size,
                              hipStream_t stream)
{
  const float* x     = (const float*)d_in[0];
  const int*   cu    = (const int*)d_in[1];
  const float* freqs = (const float*)d_in[2];
  const float* wq    = (const float*)d_in[3];
  const float* bq    = (const float*)d_in[4];
  const float* wp    = (const float*)d_in[5];
  const float* bp    = (const float*)d_in[6];
  (void)in_sizes; (void)n_in; (void)out_size; (void)ws_size;

  char* ws = (char*)d_ws;
  // ws arena (73,269,248 bytes total), all offsets 16B-aligned
  bf16*  xb   = (bf16*)(ws + 0);          //  7,864,320  x as bf16
  bf16*  wqb  = (bf16*)(ws + 7864320);    //  9,830,400  w_qkv bf16
  bf16*  wpb  = (bf16*)(ws + 17694720);   //  3,276,800  w_proj bf16
  float* cost = (float*)(ws + 20971520);  //    983,040  cos table (S,80)
  float* sint = (float*)(ws + 21954560);  //    983,040  sin table
  bf16*  qkvb = (bf16*)(ws + 22937600);   // 23,592,960  qkv bf16 (S,3840)
  bf16*  Qb   = (bf16*)(ws + 46530560);   //  9,437,184  roped Q (h,s,96)
  bf16*  Kb   = (bf16*)(ws + 55967744);   //  9,437,184  roped K (h,s,96)
  bf16*  ctxb = (bf16*)(ws + 65404928);   //  7,864,320  attn output (S,1280)

  prep_kernel<<<4096, 256, 0, stream>>>(x, wq, wp, freqs, xb, wqb, wpb, cost, sint);
  gemm_bt<1><<<dim3(F3 / 128, S_LEN / 128), 256, 0, stream>>>(
      xb, wqb, bq, qkvb, S_LEN, F3, E_DIM);
  rope_kernel<<<4096, 256, 0, stream>>>(qkvb, cost, sint, Qb, Kb);
  attn_kernel<<<N_SEG * H_NUM * 8, 256, 0, stream>>>(Qb, Kb, qkvb, cu, ctxb);
  gemm_bt<0><<<dim3(E_DIM / 128, S_LEN / 128), 256, 0, stream>>>(
      ctxb, wpb, bp, d_out, S_LEN, E_DIM, E_DIM);
}

// Round 2
// 135.084 us; speedup vs baseline: 1.1132x; 1.1132x over previous
//
#include <hip/hip_runtime.h>

typedef __bf16 bf16;
typedef __bf16 bf16x4 __attribute__((ext_vector_type(4)));
typedef __bf16 bf16x8 __attribute__((ext_vector_type(8)));
typedef float f32x4 __attribute__((ext_vector_type(4)));

#define S_LEN 3072
#define E_DIM 1280
#define H_NUM 16
#define D_DIM 80
#define D_PAD 96
#define F3 3840
#define N_SEG 6

__device__ __forceinline__ f32x4 mfma16(bf16x8 a, bf16x8 b, f32x4 c) {
  return __builtin_amdgcn_mfma_f32_16x16x32_bf16(a, b, c, 0, 0, 0);
}

using gas_void = const __attribute__((address_space(1))) void;
using las_void = __attribute__((address_space(3))) void;

__device__ __forceinline__ void async_cp16(const void* g, void* l) {
  // global -> LDS direct copy, 16B per lane; LDS dest = wave-uniform base + lane*16
  __builtin_amdgcn_global_load_lds((gas_void*)g, (las_void*)l, 16, 0, 0);
}

// ---------------- prep: fp32->bf16 casts + rope cos/sin tables (vectorized x4) ----------------
__global__ void prep_kernel(const float* __restrict__ x, const float* __restrict__ wq,
                            const float* __restrict__ wp, const float* __restrict__ freqs,
                            bf16* __restrict__ xb, bf16* __restrict__ wqb,
                            bf16* __restrict__ wpb, float* __restrict__ cost,
                            float* __restrict__ sint)
{
  const int NX4 = (S_LEN * E_DIM) / 4;
  const int NWQ4 = (F3 * E_DIM) / 4;
  const int NWP4 = (E_DIM * E_DIM) / 4;
  const int NCS4 = (S_LEN * D_DIM) / 4;
  const int total4 = NX4 + NWQ4 + NWP4 + NCS4;
  int i = blockIdx.x * blockDim.x + threadIdx.x;
  if (i >= total4) return;
  if (i < NX4) {
    f32x4 v = ((const f32x4*)x)[i];
    bf16x4 r = {(bf16)v[0], (bf16)v[1], (bf16)v[2], (bf16)v[3]};
    ((bf16x4*)xb)[i] = r;
  } else if (i < NX4 + NWQ4) {
    int j = i - NX4;
    f32x4 v = ((const f32x4*)wq)[j];
    bf16x4 r = {(bf16)v[0], (bf16)v[1], (bf16)v[2], (bf16)v[3]};
    ((bf16x4*)wqb)[j] = r;
  } else if (i < NX4 + NWQ4 + NWP4) {
    int j = i - NX4 - NWQ4;
    f32x4 v = ((const f32x4*)wp)[j];
    bf16x4 r = {(bf16)v[0], (bf16)v[1], (bf16)v[2], (bf16)v[3]};
    ((bf16x4*)wpb)[j] = r;
  } else {
    int j4 = i - NX4 - NWQ4 - NWP4;
    int j = j4 * 4;
    int s = j / D_DIM, d0 = j - s * D_DIM;  // d0 in {0,4,...,76}, same half for all 4
    f32x4 f = *(const f32x4*)&freqs[s * (D_DIM / 2) + (d0 % (D_DIM / 2))];
    f32x4 cv, sv;
#pragma unroll
    for (int t = 0; t < 4; ++t) {
      float c, s2;
      __sincosf(f[t], &s2, &c);
      cv[t] = c; sv[t] = s2;
    }
    *(f32x4*)&cost[j] = cv;
    *(f32x4*)&sint[j] = sv;
  }
}

// ---------------- GEMM: C[M,N] = A[M,K] * B[N,K]^T + bias, 128x128 tile ----------------
template <int OUT_BF16>
__global__ __launch_bounds__(256) void gemm_bt(const bf16* __restrict__ A,
                                               const bf16* __restrict__ B,
                                               const float* __restrict__ bias,
                                               void* __restrict__ Cout,
                                               int M, int N, int K)
{
  __shared__ bf16 Asm[2][128 * 32];
  __shared__ bf16 Bsm[2][128 * 32];
  const int tid = threadIdx.x;
  const int w = tid >> 6, lane = tid & 63;
  const int lr = lane & 15, lg = lane >> 4;
  const int m0 = blockIdx.y * 128, n0 = blockIdx.x * 128;
  const int wr = w >> 1, wc = w & 1;
  (void)M;

  const f32x4 zero4 = {0.f, 0.f, 0.f, 0.f};
  f32x4 acc[4][4];
#pragma unroll
  for (int m = 0; m < 4; ++m)
#pragma unroll
    for (int n = 0; n < 4; ++n) acc[m][n] = zero4;

  const int srow = lane >> 2;        // 0..15
  const int skk = (lane & 3) * 8;    // 0,8,16,24
  const int nk = K / 32;

  {
    const bf16* Ag = A + (size_t)(m0 + w * 32 + srow) * K + skk;
    const bf16* Bg = B + (size_t)(n0 + w * 32 + srow) * K + skk;
    async_cp16(Ag, &Asm[0][w * 1024]);
    async_cp16(Ag + (size_t)16 * K, &Asm[0][w * 1024 + 512]);
    async_cp16(Bg, &Bsm[0][w * 1024]);
    async_cp16(Bg + (size_t)16 * K, &Bsm[0][w * 1024 + 512]);
  }
  for (int t = 0; t < nk; ++t) {
    __syncthreads();  // drains vmcnt: tile t staged; prev compute reads done
    if (t + 1 < nk) {
      const int b = (t + 1) & 1;
      const bf16* Ag = A + (size_t)(m0 + w * 32 + srow) * K + (t + 1) * 32 + skk;
      const bf16* Bg = B + (size_t)(n0 + w * 32 + srow) * K + (t + 1) * 32 + skk;
      async_cp16(Ag, &Asm[b][w * 1024]);
      async_cp16(Ag + (size_t)16 * K, &Asm[b][w * 1024 + 512]);
      async_cp16(Bg, &Bsm[b][w * 1024]);
      async_cp16(Bg + (size_t)16 * K, &Bsm[b][w * 1024 + 512]);
    }
    const bf16* As = Asm[t & 1];
    const bf16* Bs = Bsm[t & 1];
    bf16x8 af[4], bfr[4];
#pragma unroll
    for (int m = 0; m < 4; ++m)
      af[m] = *(const bf16x8*)&As[(wr * 64 + m * 16 + lr) * 32 + lg * 8];
#pragma unroll
    for (int n = 0; n < 4; ++n)
      bfr[n] = *(const bf16x8*)&Bs[(wc * 64 + n * 16 + lr) * 32 + lg * 8];
#pragma unroll
    for (int m = 0; m < 4; ++m)
#pragma unroll
      for (int n = 0; n < 4; ++n)
        acc[m][n] = mfma16(af[m], bfr[n], acc[m][n]);
  }

#pragma unroll
  for (int m = 0; m < 4; ++m) {
    const int row = m0 + wr * 64 + m * 16 + lg * 4;  // C row=(lane>>4)*4+reg, col=lane&15
#pragma unroll
    for (int n = 0; n < 4; ++n) {
      const int col = n0 + wc * 64 + n * 16 + lr;
      const float bv = bias[col];
#pragma unroll
      for (int i = 0; i < 4; ++i) {
        float v = acc[m][n][i] + bv;
        if (OUT_BF16)
          ((bf16*)Cout)[(size_t)(row + i) * N + col] = (bf16)v;
        else
          ((float*)Cout)[(size_t)(row + i) * N + col] = v;
      }
    }
  }
}

// ---------------- RoPE (vectorized bf16x8): qkv -> Qb/Kb (h, s, 96), scale folded into Q ----------------
__global__ void rope_kernel(const bf16* __restrict__ qkv, const float* __restrict__ cost,
                            const float* __restrict__ sint, bf16* __restrict__ Qb,
                            bf16* __restrict__ Kb)
{
  const float scale = 0.11180339887498949f;  // 1/sqrt(80)
  int i = blockIdx.x * blockDim.x + threadIdx.x;  // (h, s, chunk) chunks of 8
  if (i >= H_NUM * S_LEN * 12) return;
  int c = i % 12;
  int sh = i / 12;
  int s = sh % S_LEN, h = sh / S_LEN;
  size_t od = ((size_t)h * S_LEN + s) * D_PAD + c * 8;
  if (c >= 10) {  // pad region d 80..95
    bf16x8 z = {};
    *(bf16x8*)&Qb[od] = z;
    *(bf16x8*)&Kb[od] = z;
    return;
  }
  int d0 = c * 8;
  size_t base = (size_t)s * F3 + h * D_DIM;
  bf16x8 qv = *(const bf16x8*)&qkv[base + d0];
  bf16x8 kv = *(const bf16x8*)&qkv[base + E_DIM + d0];
  int rot = (d0 < 40) ? d0 + 40 : d0 - 40;
  float sgn = (d0 < 40) ? -1.f : 1.f;
  bf16x8 qr = *(const bf16x8*)&qkv[base + rot];
  bf16x8 kr = *(const bf16x8*)&qkv[base + E_DIM + rot];
  float cc[8], ss[8];
  *(f32x4*)&cc[0] = *(const f32x4*)&cost[s * D_DIM + d0];
  *(f32x4*)&cc[4] = *(const f32x4*)&cost[s * D_DIM + d0 + 4];
  *(f32x4*)&ss[0] = *(const f32x4*)&sint[s * D_DIM + d0];
  *(f32x4*)&ss[4] = *(const f32x4*)&sint[s * D_DIM + d0 + 4];
  bf16x8 qo, ko;
#pragma unroll
  for (int j = 0; j < 8; ++j) {
    qo[j] = (bf16)(((float)qv[j] * cc[j] + sgn * (float)qr[j] * ss[j]) * scale);
    ko[j] = (bf16)((float)kv[j] * cc[j] + sgn * (float)kr[j] * ss[j]);
  }
  *(bf16x8*)&Qb[od] = qo;
  *(bf16x8*)&Kb[od] = ko;
}

// ---------------- flash attention within segments; 4 waves x 16 q-rows ----------------
__global__ __launch_bounds__(256) void attn_kernel(const bf16* __restrict__ Qb,
                                                   const bf16* __restrict__ Kb,
                                                   const bf16* __restrict__ qkv,
                                                   const int* __restrict__ cu,
                                                   bf16* __restrict__ ctx)
{
  __shared__ bf16 Ksm[64 * 104];      // K tile, stride 104 (bank-conflict-free b128)
  __shared__ bf16 Vsm[80 * 72];       // V^T tile [d][n], stride 72
  __shared__ bf16 Psm[4][16 * 72];    // per-wave P round-trip, stride 72

  const int tid = threadIdx.x;
  const int w = tid >> 6, lane = tid & 63;
  const int lr = lane & 15, lg = lane >> 4;
  const int bid = blockIdx.x;
  const int qt = bid & 7, h = (bid >> 3) & 15, seg = bid >> 7;
  const int s0 = cu[seg];
  const int q0 = s0 + qt * 64 + w * 16;

  bf16x8 qf[3];  // A-frag: row = lane&15, k = (lane>>4)*8 + j (+32 per chunk)
#pragma unroll
  for (int c = 0; c < 3; ++c)
    qf[c] = *(const bf16x8*)&Qb[((size_t)h * S_LEN + q0 + lr) * D_PAD + c * 32 + lg * 8];

  const f32x4 zero4 = {0.f, 0.f, 0.f, 0.f};
  float m_i[4] = {-1e30f, -1e30f, -1e30f, -1e30f};
  float l_i[4] = {0.f, 0.f, 0.f, 0.f};
  f32x4 o[5];
#pragma unroll
  for (int db = 0; db < 5; ++db) o[db] = zero4;

  for (int kt = 0; kt < 8; ++kt) {
    const int n0 = s0 + kt * 64;
    // stage K tile: 64 rows x 96 elems in 8-elem chunks (768 chunks / 256 thr)
#pragma unroll
    for (int it = 0; it < 3; ++it) {
      int q = tid + it * 256;
      int row = q / 12, sd = (q % 12) * 8;
      *(bf16x8*)&Ksm[row * 104 + sd] =
          *(const bf16x8*)&Kb[((size_t)h * S_LEN + n0 + row) * D_PAD + sd];
    }
    // stage V^T: transpose via coalesced column reads from global (L2-hot),
    // one conflict-free b128 LDS write per thread (bank = 4*d mod 32).
#pragma unroll
    for (int it = 0; it < 3; ++it) {
      int q = tid + it * 256;
      if (q < 640) {
        int d = q % 80, kb8 = (q / 80) * 8;
        const bf16* src = &qkv[(size_t)(n0 + kb8) * F3 + 2560 + h * D_DIM + d];
        bf16x8 v;
#pragma unroll
        for (int j = 0; j < 8; ++j) v[j] = src[(size_t)j * F3];
        *(bf16x8*)&Vsm[d * 72 + kb8] = v;
      }
    }
    __syncthreads();

    // S = Q K^T (scale pre-folded into Q); 4 col-blocks of 16
    f32x4 sa[4];
#pragma unroll
    for (int nb = 0; nb < 4; ++nb) {
      sa[nb] = zero4;
#pragma unroll
      for (int c = 0; c < 3; ++c) {
        bf16x8 kf = *(const bf16x8*)&Ksm[(nb * 16 + lr) * 104 + c * 32 + lg * 8];
        sa[nb] = mfma16(qf[c], kf, sa[nb]);
      }
    }

    // online softmax: row i lives in lanes sharing lg; reduce across lr (16-lane groups)
    float al[4];
#pragma unroll
    for (int i = 0; i < 4; ++i) {
      float tm = fmaxf(fmaxf(sa[0][i], sa[1][i]), fmaxf(sa[2][i], sa[3][i]));
#pragma unroll
      for (int off = 1; off < 16; off <<= 1) tm = fmaxf(tm, __shfl_xor(tm, off));
      float mnew = fmaxf(m_i[i], tm);
      al[i] = __expf(m_i[i] - mnew);
      float p0 = __expf(sa[0][i] - mnew);
      float p1 = __expf(sa[1][i] - mnew);
      float p2 = __expf(sa[2][i] - mnew);
      float p3 = __expf(sa[3][i] - mnew);
      sa[0][i] = p0; sa[1][i] = p1; sa[2][i] = p2; sa[3][i] = p3;
      float rs = p0 + p1 + p2 + p3;
#pragma unroll
      for (int off = 1; off < 16; off <<= 1) rs += __shfl_xor(rs, off);
      l_i[i] = l_i[i] * al[i] + rs;
      m_i[i] = mnew;
    }
#pragma unroll
    for (int db = 0; db < 5; ++db)
#pragma unroll
      for (int i = 0; i < 4; ++i) o[db][i] *= al[i];

    // P -> LDS (C layout row=(lg*4+i), col=nb*16+lr) then re-read as A-frag
#pragma unroll
    for (int nb = 0; nb < 4; ++nb)
#pragma unroll
      for (int i = 0; i < 4; ++i)
        Psm[w][(lg * 4 + i) * 72 + nb * 16 + lr] = (bf16)sa[nb][i];

#pragma unroll
    for (int c2 = 0; c2 < 2; ++c2) {
      bf16x8 pa = *(const bf16x8*)&Psm[w][lr * 72 + c2 * 32 + lg * 8];
#pragma unroll
      for (int db = 0; db < 5; ++db) {
        bf16x8 vf = *(const bf16x8*)&Vsm[(db * 16 + lr) * 72 + c2 * 32 + lg * 8];
        o[db] = mfma16(pa, vf, o[db]);
      }
    }
    __syncthreads();
  }

#pragma unroll
  for (int i = 0; i < 4; ++i) {
    float inv = 1.f / l_i[i];
    int row = q0 + lg * 4 + i;
#pragma unroll
    for (int db = 0; db < 5; ++db)
      ctx[(size_t)row * E_DIM + h * D_DIM + db * 16 + lr] = (bf16)(o[db][i] * inv);
  }
}

extern "C" void kernel_launch(void* const* d_in, const int* in_sizes, int n_in,
                              void* d_out, int out_size, void* d_ws, size_t ws_size,
                              hipStream_t stream)
{
  const float* x     = (const float*)d_in[0];
  const int*   cu    = (const int*)d_in[1];
  const float* freqs = (const float*)d_in[2];
  const float* wq    = (const float*)d_in[3];
  const float* bq    = (const float*)d_in[4];
  const float* wp    = (const float*)d_in[5];
  const float* bp    = (const float*)d_in[6];
  (void)in_sizes; (void)n_in; (void)out_size; (void)ws_size;

  char* ws = (char*)d_ws;
  // ws arena (73,269,248 bytes total), all offsets 16B-aligned
  bf16*  xb   = (bf16*)(ws + 0);          //  7,864,320  x as bf16
  bf16*  wqb  = (bf16*)(ws + 7864320);    //  9,830,400  w_qkv bf16
  bf16*  wpb  = (bf16*)(ws + 17694720);   //  3,276,800  w_proj bf16
  float* cost = (float*)(ws + 20971520);  //    983,040  cos table (S,80)
  float* sint = (float*)(ws + 21954560);  //    983,040  sin table
  bf16*  qkvb = (bf16*)(ws + 22937600);   // 23,592,960  qkv bf16 (S,3840)
  bf16*  Qb   = (bf16*)(ws + 46530560);   //  9,437,184  roped Q (h,s,96)
  bf16*  Kb   = (bf16*)(ws + 55967744);   //  9,437,184  roped K (h,s,96)
  bf16*  ctxb = (bf16*)(ws + 65404928);   //  7,864,320  attn output (S,1280)

  const int total4 = (S_LEN * E_DIM + F3 * E_DIM + E_DIM * E_DIM + S_LEN * D_DIM) / 4;
  prep_kernel<<<(total4 + 255) / 256, 256, 0, stream>>>(x, wq, wp, freqs, xb, wqb, wpb,
                                                        cost, sint);
  gemm_bt<1><<<dim3(F3 / 128, S_LEN / 128), 256, 0, stream>>>(
      xb, wqb, bq, qkvb, S_LEN, F3, E_DIM);
  rope_kernel<<<(H_NUM * S_LEN * 12 + 255) / 256, 256, 0, stream>>>(qkvb, cost, sint, Qb, Kb);
  attn_kernel<<<N_SEG * H_NUM * 8, 256, 0, stream>>>(Qb, Kb, qkvb, cu, ctxb);
  gemm_bt<0><<<dim3(E_DIM / 128, S_LEN / 128), 256, 0, stream>>>(
      ctxb, wpb, bp, d_out, S_LEN, E_DIM, E_DIM);
}